// Round 1
// baseline (11198.389 us; speedup 1.0000x reference)
//
#include <hip/hip_runtime.h>
#include <math.h>

// ---------------------------------------------------------------------------
// CNN-LSTM video predictor, fp32 correctness-first implementation.
// Pipeline: 4x conv(s2,k4,p1)+relu -> fc(4096->128) -> encLSTM x16 ->
//           decLSTM x16 (+fc 512->128) -> fc(128->4096)+relu ->
//           4x convT(s2,k4,p1) (relu,relu,relu,sigmoid)
// ---------------------------------------------------------------------------

__device__ __forceinline__ float sigmoidf_(float x) { return 1.f / (1.f + expf(-x)); }

// direct strided conv: stride 2, k=4, pad 1, + ReLU. One thread per output elem.
__global__ void conv_s2_relu(const float* __restrict__ x, const float* __restrict__ w,
                             const float* __restrict__ b, float* __restrict__ y,
                             int N, int Ci, int Hi, int Wi, int Co, int Ho, int Wo) {
    long idx = (long)blockIdx.x * blockDim.x + threadIdx.x;
    long total = (long)N * Co * Ho * Wo;
    if (idx >= total) return;
    int ow = (int)(idx % Wo); long t = idx / Wo;
    int oh = (int)(t % Ho); t /= Ho;
    int co = (int)(t % Co); int n = (int)(t / Co);
    const float* xn = x + (long)n * Ci * Hi * Wi;
    const float* wc = w + (long)co * Ci * 16;
    float acc = b[co];
    for (int ci = 0; ci < Ci; ++ci) {
        const float* xc = xn + (long)ci * Hi * Wi;
        const float* wcc = wc + ci * 16;
#pragma unroll
        for (int kh = 0; kh < 4; ++kh) {
            int ih = oh * 2 + kh - 1;
            if ((unsigned)ih >= (unsigned)Hi) continue;
#pragma unroll
            for (int kw = 0; kw < 4; ++kw) {
                int iw = ow * 2 + kw - 1;
                if ((unsigned)iw >= (unsigned)Wi) continue;
                acc += xc[ih * Wi + iw] * wcc[kh * 4 + kw];
            }
        }
    }
    y[idx] = fmaxf(acc, 0.f);
}

// transposed conv (stride 2, k=4, pad 1 equivalent): out = 2*in.
// act: 0 = relu, 1 = sigmoid
__global__ void convt_s2(const float* __restrict__ x, const float* __restrict__ w,
                         const float* __restrict__ b, float* __restrict__ y,
                         int N, int Ci, int Hi, int Wi, int Co, int act) {
    int Ho = Hi * 2, Wo = Wi * 2;
    long idx = (long)blockIdx.x * blockDim.x + threadIdx.x;
    long total = (long)N * Co * Ho * Wo;
    if (idx >= total) return;
    int ow = (int)(idx % Wo); long t = idx / Wo;
    int oh = (int)(t % Ho); t /= Ho;
    int co = (int)(t % Co); int n = (int)(t / Co);
    const float* xn = x + (long)n * Ci * Hi * Wi;
    const float* wc = w + (long)co * Ci * 16;
    float acc = b[co];
    int kh0 = oh & 1, kw0 = ow & 1;
    for (int ci = 0; ci < Ci; ++ci) {
        const float* xc = xn + (long)ci * Hi * Wi;
        const float* wcc = wc + ci * 16;
#pragma unroll
        for (int dh = 0; dh < 2; ++dh) {
            int kh = kh0 + dh * 2;
            int ih = (oh + kh - 2) >> 1;   // (oh+kh-2) is even by parity choice
            if ((unsigned)ih >= (unsigned)Hi) continue;
#pragma unroll
            for (int dw = 0; dw < 2; ++dw) {
                int kw = kw0 + dw * 2;
                int iw = (ow + kw - 2) >> 1;
                if ((unsigned)iw >= (unsigned)Wi) continue;
                acc += xc[ih * Wi + iw] * wcc[kh * 4 + kw];
            }
        }
    }
    y[idx] = (act == 1) ? sigmoidf_(acc) : fmaxf(acc, 0.f);
}

// y[n*ostride + j] = act( sum_k x[n*K+k]*w[j*K+k] + b[j] )
// act: 0 = none, 1 = relu
__global__ void fc_kernel(const float* __restrict__ x, const float* __restrict__ w,
                          const float* __restrict__ b, float* __restrict__ y,
                          int N, int J, int K, int ostride, int act) {
    long idx = (long)blockIdx.x * blockDim.x + threadIdx.x;
    if (idx >= (long)N * J) return;
    int j = (int)(idx % J); int n = (int)(idx / J);
    const float* xr = x + (long)n * K;
    const float* wr = w + (long)j * K;
    float a0 = 0.f, a1 = 0.f, a2 = 0.f, a3 = 0.f;
    int k = 0;
    for (; k + 3 < K; k += 4) {
        a0 += xr[k] * wr[k];
        a1 += xr[k + 1] * wr[k + 1];
        a2 += xr[k + 2] * wr[k + 2];
        a3 += xr[k + 3] * wr[k + 3];
    }
    for (; k < K; ++k) a0 += xr[k] * wr[k];
    float acc = (a0 + a1) + (a2 + a3) + b[j];
    if (act == 1) acc = fmaxf(acc, 0.f);
    y[(long)n * ostride + j] = acc;
}

// one LSTM step for batch 16, hidden 512, input 128. One thread per (n, j).
// x row n at x + n*xstride (length 128). h ping-pongs; c indexed per-element.
__global__ void lstm_step_kernel(const float* __restrict__ x, int xstride,
                                 const float* __restrict__ h_in, const float* __restrict__ c_in,
                                 const float* __restrict__ wih, const float* __restrict__ whh,
                                 const float* __restrict__ bih, const float* __restrict__ bhh,
                                 float* __restrict__ h_out, float* __restrict__ c_out) {
    int idx = blockIdx.x * blockDim.x + threadIdx.x;
    if (idx >= 16 * 512) return;
    int j = idx & 511;
    int n = idx >> 9;
    const float* xr = x + (long)n * xstride;
    const float* hr = h_in + n * 512;
    float g[4];
#pragma unroll
    for (int gi = 0; gi < 4; ++gi) {
        int row = gi * 512 + j;
        float a0 = bih[row] + bhh[row], a1 = 0.f, a2 = 0.f, a3 = 0.f;
        const float* wi = wih + (long)row * 128;
        for (int k = 0; k < 128; k += 4) {
            a0 += xr[k] * wi[k];
            a1 += xr[k + 1] * wi[k + 1];
            a2 += xr[k + 2] * wi[k + 2];
            a3 += xr[k + 3] * wi[k + 3];
        }
        const float* wh = whh + (long)row * 512;
        for (int k = 0; k < 512; k += 4) {
            a0 += hr[k] * wh[k];
            a1 += hr[k + 1] * wh[k + 1];
            a2 += hr[k + 2] * wh[k + 2];
            a3 += hr[k + 3] * wh[k + 3];
        }
        g[gi] = (a0 + a1) + (a2 + a3);
    }
    float ig = sigmoidf_(g[0]);
    float fg = sigmoidf_(g[1]);
    float gg = tanhf(g[2]);
    float og = sigmoidf_(g[3]);
    float c = fg * c_in[idx] + ig * gg;
    h_out[idx] = og * tanhf(c);
    c_out[idx] = c;
}

static inline int cdiv_l(long n, int b) { return (int)((n + b - 1) / b); }

extern "C" void kernel_launch(void* const* d_in, const int* in_sizes, int n_in,
                              void* d_out, int out_size, void* d_ws, size_t ws_size,
                              hipStream_t stream) {
    (void)in_sizes; (void)n_in; (void)out_size; (void)ws_size;
    const float* video  = (const float*)d_in[0];
    const float* ec1_w  = (const float*)d_in[2];  const float* ec1_b = (const float*)d_in[3];
    const float* ec2_w  = (const float*)d_in[4];  const float* ec2_b = (const float*)d_in[5];
    const float* ec3_w  = (const float*)d_in[6];  const float* ec3_b = (const float*)d_in[7];
    const float* ec4_w  = (const float*)d_in[8];  const float* ec4_b = (const float*)d_in[9];
    const float* fcmu_w = (const float*)d_in[10]; const float* fcmu_b = (const float*)d_in[11];
    const float* dfc_w  = (const float*)d_in[12]; const float* dfc_b = (const float*)d_in[13];
    const float* dt1_w  = (const float*)d_in[14]; const float* dt1_b = (const float*)d_in[15];
    const float* dt2_w  = (const float*)d_in[16]; const float* dt2_b = (const float*)d_in[17];
    const float* dt3_w  = (const float*)d_in[18]; const float* dt3_b = (const float*)d_in[19];
    const float* dt4_w  = (const float*)d_in[20]; const float* dt4_b = (const float*)d_in[21];
    const float* wih_e  = (const float*)d_in[22]; const float* whh_e = (const float*)d_in[23];
    const float* bih_e  = (const float*)d_in[24]; const float* bhh_e = (const float*)d_in[25];
    const float* wih_d  = (const float*)d_in[26]; const float* whh_d = (const float*)d_in[27];
    const float* bih_d  = (const float*)d_in[28]; const float* bhh_d = (const float*)d_in[29];
    const float* fc_w   = (const float*)d_in[30]; const float* fc_b  = (const float*)d_in[31];

    float* ws = (float*)d_ws;
    float* a1 = ws;               // 8,388,608 floats: conv1 out / dt3 out
    float* a2 = ws + 8388608;     // 4,194,304: conv2 out / dt2 out
    float* a3 = ws + 12582912;    // 2,097,152: conv3 out / dt1 out
    float* a4 = ws + 14680064;    // 1,048,576: conv4 out / dfc out
    float* z  = ws + 15728640;    // 32768: encoder z  [b*16+t, 128]
    float* zs = ws + 15761408;    // 32768: decoder zs [b*16+t, 128]
    float* hA = ws + 15794176;    // 8192 each: h ping/pong, c ping/pong
    float* hB = hA + 8192;
    float* cA = hB + 8192;
    float* cB = cA + 8192;

    // zero initial LSTM state (hA, hB, cA, cB region)
    hipMemsetAsync(hA, 0, 4 * 8192 * sizeof(float), stream);

    // ---------------- encoder CNN ----------------
    conv_s2_relu<<<cdiv_l(256L*32*32*32, 256), 256, 0, stream>>>(video, ec1_w, ec1_b, a1, 256, 3, 64, 64, 32, 32, 32);
    conv_s2_relu<<<cdiv_l(256L*64*16*16, 256), 256, 0, stream>>>(a1, ec2_w, ec2_b, a2, 256, 32, 32, 32, 64, 16, 16);
    conv_s2_relu<<<cdiv_l(256L*128*8*8, 256), 256, 0, stream>>>(a2, ec3_w, ec3_b, a3, 256, 64, 16, 16, 128, 8, 8);
    conv_s2_relu<<<cdiv_l(256L*256*4*4, 256), 256, 0, stream>>>(a3, ec4_w, ec4_b, a4, 256, 128, 8, 8, 256, 4, 4);
    // fcmu: [256,4096] -> [256,128]
    fc_kernel<<<cdiv_l(256L*128, 256), 256, 0, stream>>>(a4, fcmu_w, fcmu_b, z, 256, 128, 4096, 128, 0);

    // ---------------- encoder LSTM (16 steps) ----------------
    float* hin = hA; float* hout = hB; float* cin = cA; float* cout = cB;
    for (int t = 0; t < 16; ++t) {
        lstm_step_kernel<<<32, 256, 0, stream>>>(z + t * 128, 2048, hin, cin,
                                                 wih_e, whh_e, bih_e, bhh_e, hout, cout);
        float* tmp;
        tmp = hin; hin = hout; hout = tmp;
        tmp = cin; cin = cout; cout = tmp;
    }

    // ---------------- decoder LSTM (16 steps, autoregressive) ----------------
    for (int t = 0; t < 16; ++t) {
        const float* xin = (t == 0) ? (z + 15 * 128) : (zs + (t - 1) * 128);
        lstm_step_kernel<<<32, 256, 0, stream>>>(xin, 2048, hin, cin,
                                                 wih_d, whh_d, bih_d, bhh_d, hout, cout);
        float* tmp;
        tmp = hin; hin = hout; hout = tmp;
        tmp = cin; cin = cout; cout = tmp;
        // out_t = h @ fc_w.T + fc_b -> zs[:, t] (row stride 2048)
        fc_kernel<<<cdiv_l(16L*128, 256), 256, 0, stream>>>(hin, fc_w, fc_b, zs + t * 128, 16, 128, 512, 2048, 0);
    }

    // ---------------- decoder CNN ----------------
    // dfc: [256,128] -> [256,4096] + relu
    fc_kernel<<<cdiv_l(256L*4096, 256), 256, 0, stream>>>(zs, dfc_w, dfc_b, a4, 256, 4096, 128, 4096, 1);
    convt_s2<<<cdiv_l(256L*128*8*8, 256), 256, 0, stream>>>(a4, dt1_w, dt1_b, a3, 256, 256, 4, 4, 128, 0);
    convt_s2<<<cdiv_l(256L*64*16*16, 256), 256, 0, stream>>>(a3, dt2_w, dt2_b, a2, 256, 128, 8, 8, 64, 0);
    convt_s2<<<cdiv_l(256L*32*32*32, 256), 256, 0, stream>>>(a2, dt3_w, dt3_b, a1, 256, 64, 16, 16, 32, 0);
    convt_s2<<<cdiv_l(256L*3*64*64, 256), 256, 0, stream>>>(a1, dt4_w, dt4_b, (float*)d_out, 256, 32, 32, 32, 3, 1);
}

// Round 2
// 1948.726 us; speedup vs baseline: 5.7465x; 5.7465x over previous
//
#include <hip/hip_runtime.h>
#include <math.h>

// ---------------------------------------------------------------------------
// CNN-LSTM video predictor, fp32, round 2: LDS-tiled convs, coalesced fused
// LSTM chain with decoder-FC folded into recurrent weights.
// ---------------------------------------------------------------------------

__device__ __forceinline__ float sig_(float x) { return 1.f / (1.f + expf(-x)); }

// LSTM column permutation: block b (of 64) owns j in [8b, 8b+8); within-block
// col i = g*8 + jl maps to original gate row g*512 + 8b + jl. c = 32b + i.
__device__ __forceinline__ int orig_row(int c) {
    return ((c >> 3) & 3) * 512 + (c >> 5) * 8 + (c & 7);
}

// ======================= encoder conv (s2, k4, p1, relu) ====================
template<int CI, int HI, int WI, int CO, int COB, int COT, int OWT, int CICH>
__global__ __launch_bounds__(256)
void conv_enc(const float* __restrict__ x, const float* __restrict__ w,
              const float* __restrict__ bias, float* __restrict__ y) {
    constexpr int HO = HI / 2, WO = WI / 2;
    constexpr int GROUPS = COB / COT, SPT = 256 / GROUPS;
    constexpr int SPB = SPT * OWT;
    constexpr int TILES = (HO * WO) / SPB;
    constexpr int COBS = CO / COB;
    int bid = blockIdx.x;
    int tile = bid % TILES; bid /= TILES;
    int cob = bid % COBS;   int n = bid / COBS;
    int tid = threadIdx.x;
    int cog = tid / SPT, sp = tid % SPT;
    int sidx = (tile * SPT + sp) * OWT;
    int oh = sidx / WO, ow0 = sidx % WO;

    __shared__ float wl[COB * CICH * 16];
    float acc[COT][OWT];
#pragma unroll
    for (int a = 0; a < COT; ++a)
#pragma unroll
        for (int q = 0; q < OWT; ++q) acc[a][q] = 0.f;

    const float* xn = x + (long)n * CI * HI * WI;
    for (int cc = 0; cc < CI; cc += CICH) {
        __syncthreads();
        for (int i = tid; i < COB * CICH * 16; i += 256) {
            int k = i & 15, ci = (i >> 4) % CICH, co = i / (16 * CICH);
            wl[i] = w[((cob * COB + co) * CI + cc + ci) * 16 + k];
        }
        __syncthreads();
        for (int ci = 0; ci < CICH; ++ci) {
            const float* xc = xn + (long)(cc + ci) * HI * WI;
            float patch[4][2 * OWT + 2];
#pragma unroll
            for (int r = 0; r < 4; ++r) {
                int ih = 2 * oh + r - 1;
                bool rv = (ih >= 0) && (ih < HI);
#pragma unroll
                for (int cx = 0; cx < 2 * OWT + 2; ++cx) {
                    int iw = 2 * ow0 + cx - 1;
                    patch[r][cx] = (rv && iw >= 0 && iw < WI) ? xc[ih * WI + iw] : 0.f;
                }
            }
#pragma unroll
            for (int ct = 0; ct < COT; ++ct) {
                const float* wp = &wl[((cog * COT + ct) * CICH + ci) * 16];
                float wr[16];
#pragma unroll
                for (int k = 0; k < 16; ++k) wr[k] = wp[k];
#pragma unroll
                for (int q = 0; q < OWT; ++q) {
                    float s = acc[ct][q];
#pragma unroll
                    for (int kh = 0; kh < 4; ++kh)
#pragma unroll
                        for (int kw = 0; kw < 4; ++kw)
                            s += patch[kh][2 * q + kw] * wr[kh * 4 + kw];
                    acc[ct][q] = s;
                }
            }
        }
    }
    for (int ct = 0; ct < COT; ++ct) {
        int co = cob * COB + cog * COT + ct;
        float bv = bias[co];
        for (int q = 0; q < OWT; ++q) {
            float v = fmaxf(acc[ct][q] + bv, 0.f);
            y[(((long)n * CO + co) * HO + oh) * WO + ow0 + q] = v;
        }
    }
}

// ================= decoder transposed conv (s2, k4, p1-equiv) ===============
template<int CI, int HI, int WI, int CO, int COB, int COT, int OQT, int CICH, int ACT>
__global__ __launch_bounds__(256)
void convt_dec(const float* __restrict__ x, const float* __restrict__ w,
               const float* __restrict__ bias, float* __restrict__ y) {
    constexpr int HO = HI * 2, WO = WI * 2;
    constexpr int GROUPS = COB / COT, SPT = 256 / GROUPS;
    constexpr int QPB = SPT * OQT;
    constexpr int TILES = (HI * WI) / QPB;
    constexpr int COBS = CO / COB;
    int bid = blockIdx.x;
    int tile = bid % TILES; bid /= TILES;
    int cob = bid % COBS;   int n = bid / COBS;
    int tid = threadIdx.x;
    int cog = tid / SPT, sp = tid % SPT;
    int qidx = (tile * SPT + sp) * OQT;
    int qy = qidx / WI, qx0 = qidx % WI;

    __shared__ float wl[COB * CICH * 16];
    float acc[COT][OQT * 4];
#pragma unroll
    for (int a = 0; a < COT; ++a)
#pragma unroll
        for (int q = 0; q < OQT * 4; ++q) acc[a][q] = 0.f;

    const float* xn = x + (long)n * CI * HI * WI;
    for (int cc = 0; cc < CI; cc += CICH) {
        __syncthreads();
        for (int i = tid; i < COB * CICH * 16; i += 256) {
            int k = i & 15, ci = (i >> 4) % CICH, co = i / (16 * CICH);
            wl[i] = w[((cob * COB + co) * CI + cc + ci) * 16 + k];
        }
        __syncthreads();
        for (int ci = 0; ci < CICH; ++ci) {
            const float* xc = xn + (long)(cc + ci) * HI * WI;
            float patch[3][OQT + 2];
#pragma unroll
            for (int r = 0; r < 3; ++r) {
                int ih = qy + r - 1;
                bool rv = (ih >= 0) && (ih < HI);
#pragma unroll
                for (int cx = 0; cx < OQT + 2; ++cx) {
                    int iw = qx0 + cx - 1;
                    patch[r][cx] = (rv && iw >= 0 && iw < WI) ? xc[ih * WI + iw] : 0.f;
                }
            }
#pragma unroll
            for (int ct = 0; ct < COT; ++ct) {
                const float* wp = &wl[((cog * COT + ct) * CICH + ci) * 16];
                float wr[16];
#pragma unroll
                for (int k = 0; k < 16; ++k) wr[k] = wp[k];
#pragma unroll
                for (int q = 0; q < OQT; ++q)
#pragma unroll
                    for (int p = 0; p < 2; ++p)
#pragma unroll
                        for (int qq = 0; qq < 2; ++qq) {
                            float s = acc[ct][q * 4 + p * 2 + qq];
#pragma unroll
                            for (int dh = 0; dh < 2; ++dh)
#pragma unroll
                                for (int dw = 0; dw < 2; ++dw)
                                    s += patch[p + dh][q + qq + dw] * wr[(p + 2 * dh) * 4 + (qq + 2 * dw)];
                            acc[ct][q * 4 + p * 2 + qq] = s;
                        }
            }
        }
    }
    for (int ct = 0; ct < COT; ++ct) {
        int co = cob * COB + cog * COT + ct;
        float bv = bias[co];
        for (int q = 0; q < OQT; ++q)
            for (int p = 0; p < 2; ++p)
                for (int qq = 0; qq < 2; ++qq) {
                    float v = acc[ct][q * 4 + p * 2 + qq] + bv;
                    v = (ACT == 1) ? sig_(v) : fmaxf(v, 0.f);
                    y[(((long)n * CO + co) * HO + 2 * qy + p) * WO + 2 * (qx0 + q) + qq] = v;
                }
    }
}

// ====================== generic transpose: out[c*R+r] = in[r*C+c] ===========
__global__ void transp(const float* __restrict__ in, float* __restrict__ out,
                       int R, int C) {
    long idx = (long)blockIdx.x * 256 + threadIdx.x;
    if (idx >= (long)R * C) return;
    int r = (int)(idx % R), c = (int)(idx / R);
    out[idx] = in[(long)r * C + c];
}

// permuted transpose of wih: out[m*2048 + c] = wih[orig(c)*128 + m]
__global__ void perm_wih(const float* __restrict__ wih, float* __restrict__ out) {
    int idx = blockIdx.x * 256 + threadIdx.x;  // < 262144
    int c = idx & 2047, m = idx >> 11;
    out[idx] = wih[orig_row(c) * 128 + m];
}

// permute+pack whh: out float4[k4*2048 + c] = whh[orig(c)][4k4..4k4+3]
__global__ void pack_whh(const float* __restrict__ whh, float4* __restrict__ out) {
    int idx = blockIdx.x * 256 + threadIdx.x;  // < 262144
    int c = idx & 2047, k4 = idx >> 11;
    const float4* src = (const float4*)(whh + orig_row(c) * 512);
    out[idx] = src[k4];
}

// merged decoder recurrent weights: Wcomb[k][c] = whh_d[orig(c)][k]
//   + sum_m fc_w[m][k] * wih_d[orig(c)][m] ; packed-f4 layout
__global__ __launch_bounds__(256)
void merge_dc(const float* __restrict__ wih_d, const float* __restrict__ fc_w,
              const float* __restrict__ whh_d, float* __restrict__ out) {
    int cb = (blockIdx.x >> 3) * 64, kb = (blockIdx.x & 7) * 64;
    int tid = threadIdx.x;
    int cgl = (tid & 15) * 4, kgl = (tid >> 4) * 4;
    __shared__ float At[64][65];
    __shared__ float Bt[64][65];
    float acc[4][4] = {};
    for (int mc = 0; mc < 128; mc += 64) {
        __syncthreads();
        for (int i = tid; i < 4096; i += 256) {
            int cl = i >> 6, m = i & 63;
            At[cl][m] = wih_d[orig_row(cb + cl) * 128 + mc + m];
            Bt[cl][m] = fc_w[(mc + cl) * 512 + kb + m];
        }
        __syncthreads();
        for (int m = 0; m < 64; ++m) {
            float a[4], b[4];
#pragma unroll
            for (int i = 0; i < 4; ++i) { a[i] = At[cgl + i][m]; b[i] = Bt[m][kgl + i]; }
#pragma unroll
            for (int i = 0; i < 4; ++i)
#pragma unroll
                for (int j = 0; j < 4; ++j) acc[i][j] += a[i] * b[j];
        }
    }
    for (int i = 0; i < 4; ++i) {
        int c = cb + cgl + i; int orow = orig_row(c);
        for (int j = 0; j < 4; ++j) {
            int k = kb + kgl + j;
            out[((k >> 2) * 2048 + c) * 4 + (k & 3)] = acc[i][j] + whh_d[orow * 512 + k];
        }
    }
}

// decoder steady-state bias: bih+bhh + fc_b @ wih_d^T (permuted index)
__global__ void biasdc_k(const float* __restrict__ bih, const float* __restrict__ bhh,
                         const float* __restrict__ wih_d, const float* __restrict__ fc_b,
                         float* __restrict__ out) {
    int c = blockIdx.x * 256 + threadIdx.x;
    if (c >= 2048) return;
    int orow = orig_row(c);
    float s = bih[orow] + bhh[orow];
    for (int m = 0; m < 128; ++m) s += fc_b[m] * wih_d[orow * 128 + m];
    out[c] = s;
}

// x-projection: out[r][c] = sum_m z[r][m]*wihP[m][c] + bih[orig]+bhh[orig]
__global__ __launch_bounds__(512)
void gx_kernel(const float* __restrict__ z, int zrstride,
               const float* __restrict__ wihP, const float* __restrict__ bih,
               const float* __restrict__ bhh, float* __restrict__ out) {
    int rg = blockIdx.x >> 2, cch = blockIdx.x & 3;
    int tid = threadIdx.x;
    __shared__ float zl[16 * 128];
    for (int i = tid; i < 2048; i += 512)
        zl[i] = z[(long)(rg * 16 + (i >> 7)) * zrstride + (i & 127)];
    __syncthreads();
    int c = cch * 512 + tid;
    int orow = orig_row(c);
    float bsum = bih[orow] + bhh[orow];
    float acc[16];
#pragma unroll
    for (int r = 0; r < 16; ++r) acc[r] = bsum;
    for (int m = 0; m < 128; ++m) {
        float wv = wihP[m * 2048 + c];
#pragma unroll
        for (int r = 0; r < 16; ++r) acc[r] += zl[r * 128 + m] * wv;
    }
    for (int r = 0; r < 16; ++r) out[(long)(rg * 16 + r) * 2048 + c] = acc[r];
}

// one LSTM step: 64 blocks x 512 threads
__global__ __launch_bounds__(512)
void lstm_step(const float4* __restrict__ wh4, const float* __restrict__ gadd,
               int gstride, const float* __restrict__ h_in, float* __restrict__ h_out,
               float* __restrict__ cst, float* __restrict__ hall) {
    __shared__ float hs[8192];
    __shared__ float gb[16][32];
    int tid = threadIdx.x;
    float4* hs4 = (float4*)hs;
    const float4* hi4 = (const float4*)h_in;
#pragma unroll
    for (int i = 0; i < 4; ++i) hs4[tid + 512 * i] = hi4[tid + 512 * i];
    __syncthreads();
    int col = tid & 31, n = tid >> 5;
    int cg = blockIdx.x * 32 + col;
    float acc = gadd[n * gstride + cg];
    const float4* wp = wh4 + cg;
    const float4* hv = (const float4*)(hs + n * 512);
#pragma unroll 8
    for (int k4 = 0; k4 < 128; ++k4) {
        float4 wv = wp[(long)k4 * 2048];
        float4 h4 = hv[k4];
        acc += wv.x * h4.x + wv.y * h4.y + wv.z * h4.z + wv.w * h4.w;
    }
    gb[n][col] = acc;
    __syncthreads();
    if (col < 8) {
        int j = blockIdx.x * 8 + col;
        float gi = sig_(gb[n][col]);
        float gf = sig_(gb[n][col + 8]);
        float gg = tanhf(gb[n][col + 16]);
        float go = sig_(gb[n][col + 24]);
        int idx = n * 512 + j;
        float cv = gf * cst[idx] + gi * gg;
        cst[idx] = cv;
        float hvv = go * tanhf(cv);
        h_out[idx] = hvv;
        if (hall) hall[idx] = hvv;
    }
}

// fcmu partial GEMM: 16 row-groups x 8 k-slices
__global__ __launch_bounds__(512)
void fcmu_part(const float* __restrict__ x, const float* __restrict__ wP,
               float* __restrict__ part) {
    int rg = blockIdx.x >> 3, ks = blockIdx.x & 7;
    int tid = threadIdx.x;
    __shared__ float xl[16 * 512];
    for (int i = tid; i < 8192; i += 512)
        xl[i] = x[(long)(rg * 16 + (i >> 9)) * 4096 + ks * 512 + (i & 511)];
    __syncthreads();
    int j = tid & 127, rq = tid >> 7;
    float acc[4] = {0, 0, 0, 0};
    for (int k = 0; k < 512; ++k) {
        float wv = wP[(ks * 512 + k) * 128 + j];
#pragma unroll
        for (int i = 0; i < 4; ++i) acc[i] += xl[(rq + 4 * i) * 512 + k] * wv;
    }
    for (int i = 0; i < 4; ++i)
        part[((long)ks * 256 + rg * 16 + rq + 4 * i) * 128 + j] = acc[i];
}

__global__ void fcmu_red(const float* __restrict__ part, const float* __restrict__ b,
                         float* __restrict__ z) {
    int idx = blockIdx.x * 256 + threadIdx.x;  // 32768
    float s = b[idx & 127];
    for (int k = 0; k < 8; ++k) s += part[k * 32768 + idx];
    z[idx] = s;
}

// zs = Hall[t] @ fc_w^T + fc_b (one block per t)
__global__ __launch_bounds__(512)
void zs_k(const float* __restrict__ hall, const float* __restrict__ fcP,
          const float* __restrict__ fcb, float* __restrict__ zs) {
    int t = blockIdx.x;
    int tid = threadIdx.x;
    __shared__ float hs[8192];
    const float* h = hall + t * 8192;
    for (int i = tid; i < 8192; i += 512) hs[i] = h[i];
    __syncthreads();
    int j = tid & 127, ng = tid >> 7;
    float acc[4] = {0, 0, 0, 0};
    for (int k = 0; k < 512; ++k) {
        float wv = fcP[k * 128 + j];
#pragma unroll
        for (int i = 0; i < 4; ++i) acc[i] += hs[(ng + 4 * i) * 512 + k] * wv;
    }
    float bv = fcb[j];
    for (int i = 0; i < 4; ++i)
        zs[((ng + 4 * i) * 16 + t) * 128 + j] = acc[i] + bv;
}

// dfc: out[r][j] = relu(sum_m zs[r][m]*dfcP[m][j] + b[j])
__global__ __launch_bounds__(512)
void dfc_k(const float* __restrict__ zs, const float* __restrict__ dP,
           const float* __restrict__ db, float* __restrict__ out) {
    int rg = blockIdx.x >> 3, jc = blockIdx.x & 7;
    int tid = threadIdx.x;
    __shared__ float zl[16 * 128];
    for (int i = tid; i < 2048; i += 512) zl[i] = zs[(long)rg * 2048 + i];
    __syncthreads();
    int j = jc * 512 + tid;
    float acc[16];
#pragma unroll
    for (int r = 0; r < 16; ++r) acc[r] = 0.f;
    for (int m = 0; m < 128; ++m) {
        float wv = dP[(long)m * 4096 + j];
#pragma unroll
        for (int r = 0; r < 16; ++r) acc[r] += zl[r * 128 + m] * wv;
    }
    float bv = db[j];
    for (int r = 0; r < 16; ++r)
        out[(long)(rg * 16 + r) * 4096 + j] = fmaxf(acc[r] + bv, 0.f);
}

extern "C" void kernel_launch(void* const* d_in, const int* in_sizes, int n_in,
                              void* d_out, int out_size, void* d_ws, size_t ws_size,
                              hipStream_t stream) {
    (void)in_sizes; (void)n_in; (void)out_size; (void)ws_size;
    const float* video  = (const float*)d_in[0];
    const float* ec1_w  = (const float*)d_in[2];  const float* ec1_b = (const float*)d_in[3];
    const float* ec2_w  = (const float*)d_in[4];  const float* ec2_b = (const float*)d_in[5];
    const float* ec3_w  = (const float*)d_in[6];  const float* ec3_b = (const float*)d_in[7];
    const float* ec4_w  = (const float*)d_in[8];  const float* ec4_b = (const float*)d_in[9];
    const float* fcmu_w = (const float*)d_in[10]; const float* fcmu_b = (const float*)d_in[11];
    const float* dfc_w  = (const float*)d_in[12]; const float* dfc_b = (const float*)d_in[13];
    const float* dt1_w  = (const float*)d_in[14]; const float* dt1_b = (const float*)d_in[15];
    const float* dt2_w  = (const float*)d_in[16]; const float* dt2_b = (const float*)d_in[17];
    const float* dt3_w  = (const float*)d_in[18]; const float* dt3_b = (const float*)d_in[19];
    const float* dt4_w  = (const float*)d_in[20]; const float* dt4_b = (const float*)d_in[21];
    const float* wih_e  = (const float*)d_in[22]; const float* whh_e = (const float*)d_in[23];
    const float* bih_e  = (const float*)d_in[24]; const float* bhh_e = (const float*)d_in[25];
    const float* wih_d  = (const float*)d_in[26]; const float* whh_d = (const float*)d_in[27];
    const float* bih_d  = (const float*)d_in[28]; const float* bhh_d = (const float*)d_in[29];
    const float* fc_w   = (const float*)d_in[30]; const float* fc_b  = (const float*)d_in[31];

    float* ws = (float*)d_ws;
    float* A1 = ws;                 // 8,388,608 floats
    float* A2 = ws + 8388608;       // 4,194,304
    float* A3 = ws + 12582912;      // 2,097,152
    float* A4 = ws + 14680064;      // 1,048,576
    float* Z      = A3;             // 32768 (A3 dead after conv4)
    float* WH4_E  = A1;             // buffers below live in A1 (dead after conv2)
    float* WH4_D0 = A1 + 1048576;
    float* WH4_DC = A1 + 2097152;
    float* GX_E   = A1 + 3145728;
    float* GX_D0  = A1 + 3670016;
    float* WIHP_E = A1 + 3702784;
    float* WIHP_D = A1 + 3964928;
    float* FCP    = A1 + 4227072;
    float* FCMUP  = A1 + 4292608;
    float* DFCP   = A1 + 4816896;
    float* BIASDC = A1 + 5341184;
    float* ZPART  = A1 + 5343232;
    float* HALL   = A1 + 5605376;
    float* HA     = A1 + 5736448;
    float* HB     = A1 + 5744640;
    float* CB     = A1 + 5752832;
    float* ZS     = A1 + 5761024;

    // ------------- encoder CNN -------------
    conv_enc<3, 64, 64, 32, 32, 8, 4, 3><<<1024, 256, 0, stream>>>(video, ec1_w, ec1_b, A1);
    conv_enc<32, 32, 32, 64, 64, 16, 4, 8><<<256, 256, 0, stream>>>(A1, ec2_w, ec2_b, A2);
    conv_enc<64, 16, 16, 128, 128, 16, 2, 4><<<256, 256, 0, stream>>>(A2, ec3_w, ec3_b, A3);
    conv_enc<128, 8, 8, 256, 128, 4, 2, 4><<<512, 256, 0, stream>>>(A3, ec4_w, ec4_b, A4);

    // ------------- weight prep (A1 free after conv2) -------------
    transp<<<2048, 256, 0, stream>>>(fcmu_w, FCMUP, 128, 4096);
    transp<<<256, 256, 0, stream>>>(fc_w, FCP, 128, 512);
    transp<<<2048, 256, 0, stream>>>(dfc_w, DFCP, 4096, 128);
    perm_wih<<<1024, 256, 0, stream>>>(wih_e, WIHP_E);
    perm_wih<<<1024, 256, 0, stream>>>(wih_d, WIHP_D);
    pack_whh<<<1024, 256, 0, stream>>>(whh_e, (float4*)WH4_E);
    pack_whh<<<1024, 256, 0, stream>>>(whh_d, (float4*)WH4_D0);
    merge_dc<<<256, 256, 0, stream>>>(wih_d, fc_w, whh_d, WH4_DC);
    biasdc_k<<<8, 256, 0, stream>>>(bih_d, bhh_d, wih_d, fc_b, BIASDC);

    // ------------- fcmu: A4 [256,4096] -> Z [256,128] -------------
    fcmu_part<<<128, 512, 0, stream>>>(A4, FCMUP, ZPART);
    fcmu_red<<<128, 256, 0, stream>>>(ZPART, fcmu_b, Z);

    // ------------- x-projections -------------
    gx_kernel<<<64, 512, 0, stream>>>(Z, 128, WIHP_E, bih_e, bhh_e, GX_E);
    gx_kernel<<<4, 512, 0, stream>>>(Z + 15 * 128, 2048, WIHP_D, bih_d, bhh_d, GX_D0);

    // ------------- LSTM chains -------------
    hipMemsetAsync(HA, 0, 3 * 8192 * sizeof(float), stream);  // HA, HB, CB
    float* hin = HA; float* hout = HB;
    for (int t = 0; t < 16; ++t) {
        lstm_step<<<64, 512, 0, stream>>>((const float4*)WH4_E, GX_E + t * 2048, 32768,
                                          hin, hout, CB, (float*)nullptr);
        float* tmp = hin; hin = hout; hout = tmp;
    }
    lstm_step<<<64, 512, 0, stream>>>((const float4*)WH4_D0, GX_D0, 2048,
                                      hin, hout, CB, HALL);
    { float* tmp = hin; hin = hout; hout = tmp; }
    for (int t = 1; t < 16; ++t) {
        lstm_step<<<64, 512, 0, stream>>>((const float4*)WH4_DC, BIASDC, 0,
                                          hin, hout, CB, HALL + t * 8192);
        float* tmp = hin; hin = hout; hout = tmp;
    }
    zs_k<<<16, 512, 0, stream>>>(HALL, FCP, fc_b, ZS);

    // ------------- decoder CNN -------------
    dfc_k<<<128, 512, 0, stream>>>(ZS, DFCP, dfc_b, A4);
    convt_dec<256, 4, 4, 128, 64, 1, 4, 8, 0><<<512, 256, 0, stream>>>(A4, dt1_w, dt1_b, A3);
    convt_dec<128, 8, 8, 64, 64, 4, 4, 8, 0><<<256, 256, 0, stream>>>(A3, dt2_w, dt2_b, A2);
    convt_dec<64, 16, 16, 32, 32, 4, 4, 16, 0><<<512, 256, 0, stream>>>(A2, dt3_w, dt3_b, A1);
    convt_dec<32, 32, 32, 3, 3, 3, 4, 32, 1><<<256, 256, 0, stream>>>(A1, dt4_w, dt4_b, (float*)d_out);
}